// Round 7
// baseline (2636.353 us; speedup 1.0000x reference)
//
#include <hip/hip_runtime.h>
#include <hip/hip_bf16.h>

#define N_NODES 50000
#define N_EDGES 1600000
#define NPB  50      // nodes per bucket
#define NBUK 1000    // NPB*NBUK == N_NODES exactly
#define BCAP 2048    // slots per bucket (mean 1600, sigma 40 -> +11 sigma)

typedef __attribute__((ext_vector_type(8))) short short8;
typedef __attribute__((ext_vector_type(4))) float f32x4;

__device__ __forceinline__ unsigned short f2bf(float f) {
  union { float f; unsigned int i; } v; v.f = f;
  unsigned int i = v.i;
  unsigned int r = i + 0x7FFFu + ((i >> 16) & 1u);
  return (unsigned short)(r >> 16);
}

// ---------------- Kernel 1: x = h @ W  (fp32 in, bf16 MFMA, f32 out) -------
__global__ __launch_bounds__(256) void k_x(const float* __restrict__ hmat,
                                           const float* __restrict__ Wmat,
                                           float* __restrict__ x) {
  __shared__ unsigned short Wt[64 * 264];  // Wt[n][k], row stride 264 (16B-aligned)
  const int t = threadIdx.x;
  for (int idx = t; idx < 64 * 256; idx += 256) {
    int k = idx >> 6, n = idx & 63;        // global read coalesced (idx = k*64+n)
    Wt[n * 264 + k] = f2bf(Wmat[idx]);
  }
  __syncthreads();
  const int wave = t >> 6, lane = t & 63;
  const int quad = lane >> 4, l16 = lane & 15;
  const int m0 = blockIdx.x * 64 + wave * 16;
  int arow = m0 + l16; if (arow >= N_NODES) arow = N_NODES - 1;  // clamp: rows independent
  f32x4 c[4] = {{0,0,0,0},{0,0,0,0},{0,0,0,0},{0,0,0,0}};
  const float* aptr = hmat + (size_t)arow * 256 + quad * 8;
  #pragma unroll
  for (int kb = 0; kb < 8; ++kb) {
    f32x4 a0 = *(const f32x4*)(aptr + kb * 32);
    f32x4 a1 = *(const f32x4*)(aptr + kb * 32 + 4);
    short8 a;
    a[0] = (short)f2bf(a0[0]); a[1] = (short)f2bf(a0[1]);
    a[2] = (short)f2bf(a0[2]); a[3] = (short)f2bf(a0[3]);
    a[4] = (short)f2bf(a1[0]); a[5] = (short)f2bf(a1[1]);
    a[6] = (short)f2bf(a1[2]); a[7] = (short)f2bf(a1[3]);
    #pragma unroll
    for (int nt = 0; nt < 4; ++nt) {
      int n = nt * 16 + l16;
      short8 b = *(const short8*)(&Wt[n * 264 + kb * 32 + quad * 8]);
      c[nt] = __builtin_amdgcn_mfma_f32_16x16x32_bf16(a, b, c[nt], 0, 0, 0);
    }
  }
  #pragma unroll
  for (int nt = 0; nt < 4; ++nt) {
    #pragma unroll
    for (int r = 0; r < 4; ++r) {
      int grow = m0 + quad * 4 + r;
      if (grow < N_NODES) x[grow * 64 + nt * 16 + l16] = c[nt][r];
    }
  }
}

// ---------------- Kernel 2: el = x@Wl^T, er = x@Wr^T (wave per row) ---------
__global__ __launch_bounds__(256) void k_eler(const float* __restrict__ x,
    const float* __restrict__ Wl, const float* __restrict__ Wr,
    float* __restrict__ el, float* __restrict__ er) {
  const int lane = threadIdx.x & 63;
  const int gw = (blockIdx.x * 256 + threadIdx.x) >> 6;
  const int nw = gridDim.x * 4;
  float wl[4], wr[4];
  #pragma unroll
  for (int hh = 0; hh < 4; ++hh) {
    wl[hh] = Wl[hh * 64 + lane];
    wr[hh] = Wr[hh * 64 + lane];
  }
  for (int r = gw; r < N_NODES; r += nw) {
    float xv = x[r * 64 + lane];
    float p[4], q[4];
    #pragma unroll
    for (int hh = 0; hh < 4; ++hh) { p[hh] = xv * wl[hh]; q[hh] = xv * wr[hh]; }
    #pragma unroll
    for (int off = 32; off > 0; off >>= 1) {
      #pragma unroll
      for (int hh = 0; hh < 4; ++hh) {
        p[hh] += __shfl_xor(p[hh], off, 64);
        q[hh] += __shfl_xor(q[hh], off, 64);
      }
    }
    if (lane == 0) {
      f32x4 pv = {p[0], p[1], p[2], p[3]};
      f32x4 qv = {q[0], q[1], q[2], q[3]};
      ((f32x4*)el)[r] = pv;
      ((f32x4*)er)[r] = qv;
    }
  }
}

// ---------------- Kernel 3: bucket partition --------------------------------
// Record = dst<<8 | src_local (dst<65536 fits 16b, src_local<50 fits 8b).
// ~1000 concurrently-active destination lines stay L2-resident -> no write amp.
__global__ __launch_bounds__(256) void k_part(const int* __restrict__ ei,
                                              int* __restrict__ bcnt,
                                              unsigned int* __restrict__ recs) {
  int e = blockIdx.x * 256 + threadIdx.x;
  if (e < N_EDGES) {
    int s = ei[e], d = ei[N_EDGES + e];
    int b  = s / NPB;
    int sl = s - b * NPB;
    int pos = atomicAdd(&bcnt[b], 1);
    if (pos < BCAP)
      recs[(size_t)b * BCAP + pos] = ((unsigned int)d << 8) | (unsigned int)sl;
  }
}

// ---------------- Kernel 4: bucket aggregate + normalize + ELU --------------
// One block per bucket; all 50 nodes' accumulators live in LDS (52 KB).
// Per edge (wave-uniform): 256B coalesced x[dst] gather + 4 LDS f32 adds + den.
__global__ __launch_bounds__(256) void k_aggB(const float* __restrict__ x,
    const float* __restrict__ el, const float* __restrict__ er,
    const int* __restrict__ bcnt, const unsigned int* __restrict__ recs,
    const float* __restrict__ bvec, float* __restrict__ out) {
  __shared__ float acc[NPB * 260];   // [node][0..255 num(h*64+d), 256..259 den]
  const int t = threadIdx.x;
  const int b = blockIdx.x;
  for (int i = t; i < NPB * 260; i += 256) acc[i] = 0.f;
  __syncthreads();
  int cnt = bcnt[b]; if (cnt > BCAP) cnt = BCAP;
  const unsigned int* rec = recs + (size_t)b * BCAP;
  const int lane = t & 63, wv = t >> 6;
  for (int j = wv; j < cnt; j += 4) {
    unsigned int r = rec[j];
    int sl = (int)(r & 255u);
    int d  = (int)(r >> 8);
    f32x4 a = ((const f32x4*)el)[b * NPB + sl];   // L1-resident (800B/bucket)
    f32x4 e = ((const f32x4*)er)[d];              // L2-resident (800 KB)
    float w0, w1, w2, w3;
    { float tt = a[0] + e[0]; tt = tt >= 0.f ? tt : 0.2f * tt; w0 = __expf(tt); }
    { float tt = a[1] + e[1]; tt = tt >= 0.f ? tt : 0.2f * tt; w1 = __expf(tt); }
    { float tt = a[2] + e[2]; tt = tt >= 0.f ? tt : 0.2f * tt; w2 = __expf(tt); }
    { float tt = a[3] + e[3]; tt = tt >= 0.f ? tt : 0.2f * tt; w3 = __expf(tt); }
    float xv = x[(size_t)d * 64 + lane];          // coalesced 256B gather
    float* ap = &acc[sl * 260];
    atomicAdd(ap + lane,       w0 * xv);          // ds_add_f32, conflict-free
    atomicAdd(ap + 64  + lane, w1 * xv);
    atomicAdd(ap + 128 + lane, w2 * xv);
    atomicAdd(ap + 192 + lane, w3 * xv);
    if (lane < 4) {
      float ws = lane == 0 ? w0 : lane == 1 ? w1 : lane == 2 ? w2 : w3;
      atomicAdd(ap + 256 + lane, ws);
    }
  }
  __syncthreads();
  // epilogue: 50 nodes x 256 outputs, coalesced
  for (int i = t; i < NPB * 256; i += 256) {
    int n = i >> 8, c = i & 255, hh = c >> 6;
    float den = acc[n * 260 + 256 + hh];
    float o = acc[n * 260 + c] / fmaxf(den, 1e-12f) + bvec[c & 63];
    o = (o > 0.f) ? o : (__expf(o) - 1.f);
    out[(size_t)(b * NPB + n) * 256 + c] = o;
  }
}

// ---------------- Launch ----------------------------------------------------
extern "C" void kernel_launch(void* const* d_in, const int* in_sizes, int n_in,
                              void* d_out, int out_size, void* d_ws, size_t ws_size,
                              hipStream_t stream) {
  const float* h  = (const float*)d_in[0];
  const float* W  = (const float*)d_in[1];
  const float* Wl = (const float*)d_in[2];
  const float* Wr = (const float*)d_in[3];
  const float* b  = (const float*)d_in[4];
  const int*   ei = (const int*)d_in[5];
  float* out = (float*)d_out;   // reference output dtype is float32

  char* ws = (char*)d_ws;
  float*        x    = (float*)       (ws + 0);          // 50000*64*4 = 12,800,000
  float*        el   = (float*)       (ws + 12800000);   // 800,000
  float*        er   = (float*)       (ws + 13600000);   // 800,000
  int*          bcnt = (int*)         (ws + 14400000);   // 1000*4 (pad 4096)
  unsigned int* recs = (unsigned int*)(ws + 14404096);   // 1000*2048*4 = 8,192,000
  (void)ws_size; (void)in_sizes; (void)n_in; (void)out_size;

  hipMemsetAsync(bcnt, 0, 4096, stream);

  k_x    <<<782,  256, 0, stream>>>(h, W, x);
  k_eler <<<782,  256, 0, stream>>>(x, Wl, Wr, el, er);
  k_part <<<6250, 256, 0, stream>>>(ei, bcnt, recs);
  k_aggB <<<NBUK, 256, 0, stream>>>(x, el, er, bcnt, recs, b, out);
}

// Round 8
// 335.629 us; speedup vs baseline: 7.8550x; 7.8550x over previous
//
#include <hip/hip_runtime.h>
#include <hip/hip_bf16.h>
#include <hip/hip_fp16.h>

#define N_NODES 50000
#define N_EDGES 1600000
#define NPB  50      // nodes per bucket
#define NBUK 1000    // NPB*NBUK == N_NODES
#define BCAP 2048    // slots per bucket (mean 1600, sigma ~40 -> +11 sigma)

typedef __attribute__((ext_vector_type(8))) short short8;
typedef __attribute__((ext_vector_type(4))) float f32x4;

__device__ __forceinline__ unsigned short f2bf(float f) {
  union { float f; unsigned int i; } v; v.f = f;
  unsigned int i = v.i;
  unsigned int r = i + 0x7FFFu + ((i >> 16) & 1u);
  return (unsigned short)(r >> 16);
}

// ---------------- Kernel 1: x = h @ W  (fp32 in, bf16 MFMA, f32 out) -------
__global__ __launch_bounds__(256) void k_x(const float* __restrict__ hmat,
                                           const float* __restrict__ Wmat,
                                           float* __restrict__ x) {
  __shared__ unsigned short Wt[64 * 264];  // Wt[n][k], row stride 264 (16B-aligned)
  const int t = threadIdx.x;
  for (int idx = t; idx < 64 * 256; idx += 256) {
    int k = idx >> 6, n = idx & 63;        // global read coalesced (idx = k*64+n)
    Wt[n * 264 + k] = f2bf(Wmat[idx]);
  }
  __syncthreads();
  const int wave = t >> 6, lane = t & 63;
  const int quad = lane >> 4, l16 = lane & 15;
  const int m0 = blockIdx.x * 64 + wave * 16;
  int arow = m0 + l16; if (arow >= N_NODES) arow = N_NODES - 1;  // clamp: rows independent
  f32x4 c[4] = {{0,0,0,0},{0,0,0,0},{0,0,0,0},{0,0,0,0}};
  const float* aptr = hmat + (size_t)arow * 256 + quad * 8;
  #pragma unroll
  for (int kb = 0; kb < 8; ++kb) {
    f32x4 a0 = *(const f32x4*)(aptr + kb * 32);
    f32x4 a1 = *(const f32x4*)(aptr + kb * 32 + 4);
    short8 a;
    a[0] = (short)f2bf(a0[0]); a[1] = (short)f2bf(a0[1]);
    a[2] = (short)f2bf(a0[2]); a[3] = (short)f2bf(a0[3]);
    a[4] = (short)f2bf(a1[0]); a[5] = (short)f2bf(a1[1]);
    a[6] = (short)f2bf(a1[2]); a[7] = (short)f2bf(a1[3]);
    #pragma unroll
    for (int nt = 0; nt < 4; ++nt) {
      int n = nt * 16 + l16;
      short8 b = *(const short8*)(&Wt[n * 264 + kb * 32 + quad * 8]);
      c[nt] = __builtin_amdgcn_mfma_f32_16x16x32_bf16(a, b, c[nt], 0, 0, 0);
    }
  }
  #pragma unroll
  for (int nt = 0; nt < 4; ++nt) {
    #pragma unroll
    for (int r = 0; r < 4; ++r) {
      int grow = m0 + quad * 4 + r;
      if (grow < N_NODES) x[grow * 64 + nt * 16 + l16] = c[nt][r];
    }
  }
}

// ---------------- Kernel 2: el = x@Wl^T, er = x@Wr^T (wave per row) ---------
__global__ __launch_bounds__(256) void k_eler(const float* __restrict__ x,
    const float* __restrict__ Wl, const float* __restrict__ Wr,
    float* __restrict__ el, float* __restrict__ er) {
  const int lane = threadIdx.x & 63;
  const int gw = (blockIdx.x * 256 + threadIdx.x) >> 6;
  const int nw = gridDim.x * 4;
  float wl[4], wr[4];
  #pragma unroll
  for (int hh = 0; hh < 4; ++hh) {
    wl[hh] = Wl[hh * 64 + lane];
    wr[hh] = Wr[hh * 64 + lane];
  }
  for (int r = gw; r < N_NODES; r += nw) {
    float xv = x[r * 64 + lane];
    float p[4], q[4];
    #pragma unroll
    for (int hh = 0; hh < 4; ++hh) { p[hh] = xv * wl[hh]; q[hh] = xv * wr[hh]; }
    #pragma unroll
    for (int off = 32; off > 0; off >>= 1) {
      #pragma unroll
      for (int hh = 0; hh < 4; ++hh) {
        p[hh] += __shfl_xor(p[hh], off, 64);
        q[hh] += __shfl_xor(q[hh], off, 64);
      }
    }
    if (lane == 0) {
      f32x4 pv = {p[0], p[1], p[2], p[3]};
      f32x4 qv = {q[0], q[1], q[2], q[3]};
      ((f32x4*)el)[r] = pv;
      ((f32x4*)er)[r] = qv;
    }
  }
}

// ---------------- Kernel 3: bucket partition --------------------------------
// 4B record = dst<<8 | src_local. Concurrent scattered writes span only
// ~1000 L2-resident destination lines -> no write amplification.
// bcnt padded to one counter per 64B line (stride 16 ints).
__global__ __launch_bounds__(256) void k_part(const int* __restrict__ ei,
                                              int* __restrict__ bcnt,
                                              unsigned int* __restrict__ raw) {
  int e = blockIdx.x * 256 + threadIdx.x;
  if (e < N_EDGES) {
    int s = ei[e], d = ei[N_EDGES + e];
    int b  = s / NPB;
    int sl = s - b * NPB;
    int pos = atomicAdd(&bcnt[b * 16], 1);
    if (pos < BCAP)
      raw[(size_t)b * BCAP + pos] = ((unsigned int)d << 8) | (unsigned int)sl;
  }
}

// ---------------- Kernel 4: per-bucket CSR + edge weights -------------------
// One block per bucket. LDS histogram over 50 nodes + serial prefix, then
// edge-parallel weight computation; 16B records written into the bucket's
// own 32KB window (single-touch, L2-resident). rs_s/rs_e give per-node ranges.
__global__ __launch_bounds__(256) void k_bucket(const unsigned int* __restrict__ raw,
    const int* __restrict__ bcnt,
    const float* __restrict__ el, const float* __restrict__ er,
    int4* __restrict__ recs, int* __restrict__ rs_s, int* __restrict__ rs_e) {
  __shared__ unsigned int sraw[BCAP];
  __shared__ int pref[NPB + 1];   // after prefix: pref[n] = #edges with sl < n
  __shared__ int cur[NPB];
  const int b = blockIdx.x, t = threadIdx.x;
  int cnt = bcnt[b * 16]; if (cnt > BCAP) cnt = BCAP;
  for (int i = t; i < NPB + 1; i += 256) pref[i] = 0;
  __syncthreads();
  for (int j = t; j < cnt; j += 256) {
    unsigned int r = raw[(size_t)b * BCAP + j];   // coalesced
    sraw[j] = r;
    atomicAdd(&pref[(int)(r & 255u) + 1], 1);
  }
  __syncthreads();
  if (t == 0) {
    int run = 0;
    #pragma unroll
    for (int n = 0; n <= NPB; ++n) { run += pref[n]; pref[n] = run; }
  }
  __syncthreads();
  if (t < NPB) {
    cur[t] = pref[t];
    rs_s[b * NPB + t] = b * BCAP + pref[t];
    rs_e[b * NPB + t] = b * BCAP + pref[t + 1];
  }
  __syncthreads();
  const int base = b * NPB;
  for (int j = t; j < cnt; j += 256) {
    unsigned int r = sraw[j];
    int sl = (int)(r & 255u);
    int d  = (int)(r >> 8);
    int pos = atomicAdd(&cur[sl], 1);
    f32x4 a = ((const f32x4*)el)[base + sl];   // L1-resident (800B/bucket)
    f32x4 e = ((const f32x4*)er)[d];           // L2-resident (800 KB)
    float w[4];
    #pragma unroll
    for (int hh = 0; hh < 4; ++hh) {
      float tt = a[hh] + e[hh];
      tt = (tt >= 0.f) ? tt : 0.2f * tt;
      w[hh] = __expf(tt);
    }
    union { __half2 h; int i; } u01, u23;
    u01.h = __floats2half2_rn(w[0], w[1]);
    u23.h = __floats2half2_rn(w[2], w[3]);
    int4 rc; rc.x = d; rc.y = u01.i; rc.z = u23.i; rc.w = 0;
    recs[(size_t)b * BCAP + pos] = rc;         // scattered within 32KB window
  }
}

// ---------------- Kernel 5: fused normalize + SpMM + ELU (R6 form) ----------
__global__ __launch_bounds__(256) void k_agg(const float* __restrict__ x,
    const int* __restrict__ rs_s, const int* __restrict__ rs_e,
    const int4* __restrict__ recs,
    const float* __restrict__ bvec, float* __restrict__ out) {
  const int node = (blockIdx.x * 256 + threadIdx.x) >> 6;
  const int lane = threadIdx.x & 63;
  if (node >= N_NODES) return;
  float n0 = 0.f, n1 = 0.f, n2 = 0.f, n3 = 0.f;
  float d0 = 0.f, d1 = 0.f, d2 = 0.f, d3 = 0.f;
  const int j0 = rs_s[node], j1 = rs_e[node];
  #pragma unroll 4
  for (int j = j0; j < j1; ++j) {
    int4 rec = recs[j];               // 16B wave-uniform broadcast
    union { int i; __half2 h; } u01, u23;
    u01.i = rec.y; u23.i = rec.z;
    float2 f01 = __half22float2(u01.h);
    float2 f23 = __half22float2(u23.h);
    float xv = x[rec.x * 64 + lane];  // coalesced 256B gather
    d0 += f01.x; d1 += f01.y; d2 += f23.x; d3 += f23.y;
    n0 = fmaf(f01.x, xv, n0); n1 = fmaf(f01.y, xv, n1);
    n2 = fmaf(f23.x, xv, n2); n3 = fmaf(f23.y, xv, n3);
  }
  float bv = bvec[lane];
  size_t ob = (size_t)node * 256 + lane;
  float o;
  o = n0 / fmaxf(d0, 1e-12f) + bv; o = (o > 0.f) ? o : (__expf(o) - 1.f); out[ob      ] = o;
  o = n1 / fmaxf(d1, 1e-12f) + bv; o = (o > 0.f) ? o : (__expf(o) - 1.f); out[ob +  64] = o;
  o = n2 / fmaxf(d2, 1e-12f) + bv; o = (o > 0.f) ? o : (__expf(o) - 1.f); out[ob + 128] = o;
  o = n3 / fmaxf(d3, 1e-12f) + bv; o = (o > 0.f) ? o : (__expf(o) - 1.f); out[ob + 192] = o;
}

// ---------------- Launch ----------------------------------------------------
extern "C" void kernel_launch(void* const* d_in, const int* in_sizes, int n_in,
                              void* d_out, int out_size, void* d_ws, size_t ws_size,
                              hipStream_t stream) {
  const float* h  = (const float*)d_in[0];
  const float* W  = (const float*)d_in[1];
  const float* Wl = (const float*)d_in[2];
  const float* Wr = (const float*)d_in[3];
  const float* b  = (const float*)d_in[4];
  const int*   ei = (const int*)d_in[5];
  float* out = (float*)d_out;   // reference output dtype is float32

  char* ws = (char*)d_ws;
  float*        x    = (float*)       (ws + 0);          // 12,800,000
  float*        el   = (float*)       (ws + 12800000);   //    800,000
  float*        er   = (float*)       (ws + 13600000);   //    800,000
  int*          bcnt = (int*)         (ws + 14400000);   // 1000*16*4 = 64,000
  unsigned int* raw  = (unsigned int*)(ws + 14464000);   // 1000*2048*4 = 8,192,000
  int4*         recs = (int4*)        (ws + 22656000);   // 1000*2048*16 = 32,768,000
  int*          rs_s = (int*)         (ws + 55424000);   // 200,000
  int*          rs_e = (int*)         (ws + 55624000);   // 200,000  (end ~55.8 MB)
  (void)ws_size; (void)in_sizes; (void)n_in; (void)out_size;

  hipMemsetAsync(bcnt, 0, 64000, stream);

  k_x      <<<782,   256, 0, stream>>>(h, W, x);
  k_eler   <<<782,   256, 0, stream>>>(x, Wl, Wr, el, er);
  k_part   <<<6250,  256, 0, stream>>>(ei, bcnt, raw);
  k_bucket <<<NBUK,  256, 0, stream>>>(raw, bcnt, el, er, recs, rs_s, rs_e);
  k_agg    <<<12500, 256, 0, stream>>>(x, rs_s, rs_e, recs, b, out);
}

// Round 9
// 314.079 us; speedup vs baseline: 8.3939x; 1.0686x over previous
//
#include <hip/hip_runtime.h>
#include <hip/hip_bf16.h>
#include <hip/hip_fp16.h>

#define N_NODES 50000
#define N_EDGES 1600000
#define NPB    50      // nodes per bucket
#define NBUK   1000    // NPB*NBUK == N_NODES
#define NSL    8       // XCD slices
#define BCAPS  320     // slots per (bucket,slice): mean 200, +8.5 sigma
#define BCAPH  1280    // 4*BCAPS, per bucket-half

typedef __attribute__((ext_vector_type(8))) short short8;
typedef __attribute__((ext_vector_type(4))) float f32x4;

__device__ __forceinline__ unsigned short f2bf(float f) {
  union { float f; unsigned int i; } v; v.f = f;
  unsigned int i = v.i;
  unsigned int r = i + 0x7FFFu + ((i >> 16) & 1u);
  return (unsigned short)(r >> 16);
}

// ---------------- Kernel 1: x = h @ W  (fp32 in, bf16 MFMA, f32 out) -------
__global__ __launch_bounds__(256) void k_x(const float* __restrict__ hmat,
                                           const float* __restrict__ Wmat,
                                           float* __restrict__ x) {
  __shared__ unsigned short Wt[64 * 264];  // Wt[n][k], row stride 264 (16B-aligned)
  const int t = threadIdx.x;
  for (int idx = t; idx < 64 * 256; idx += 256) {
    int k = idx >> 6, n = idx & 63;        // global read coalesced (idx = k*64+n)
    Wt[n * 264 + k] = f2bf(Wmat[idx]);
  }
  __syncthreads();
  const int wave = t >> 6, lane = t & 63;
  const int quad = lane >> 4, l16 = lane & 15;
  const int m0 = blockIdx.x * 64 + wave * 16;
  int arow = m0 + l16; if (arow >= N_NODES) arow = N_NODES - 1;  // clamp: rows independent
  f32x4 c[4] = {{0,0,0,0},{0,0,0,0},{0,0,0,0},{0,0,0,0}};
  const float* aptr = hmat + (size_t)arow * 256 + quad * 8;
  #pragma unroll
  for (int kb = 0; kb < 8; ++kb) {
    f32x4 a0 = *(const f32x4*)(aptr + kb * 32);
    f32x4 a1 = *(const f32x4*)(aptr + kb * 32 + 4);
    short8 a;
    a[0] = (short)f2bf(a0[0]); a[1] = (short)f2bf(a0[1]);
    a[2] = (short)f2bf(a0[2]); a[3] = (short)f2bf(a0[3]);
    a[4] = (short)f2bf(a1[0]); a[5] = (short)f2bf(a1[1]);
    a[6] = (short)f2bf(a1[2]); a[7] = (short)f2bf(a1[3]);
    #pragma unroll
    for (int nt = 0; nt < 4; ++nt) {
      int n = nt * 16 + l16;
      short8 b = *(const short8*)(&Wt[n * 264 + kb * 32 + quad * 8]);
      c[nt] = __builtin_amdgcn_mfma_f32_16x16x32_bf16(a, b, c[nt], 0, 0, 0);
    }
  }
  #pragma unroll
  for (int nt = 0; nt < 4; ++nt) {
    #pragma unroll
    for (int r = 0; r < 4; ++r) {
      int grow = m0 + quad * 4 + r;
      if (grow < N_NODES) x[grow * 64 + nt * 16 + l16] = c[nt][r];
    }
  }
}

// ---------------- Kernel 2: el = x@Wl^T, er = x@Wr^T (wave per row) ---------
__global__ __launch_bounds__(256) void k_eler(const float* __restrict__ x,
    const float* __restrict__ Wl, const float* __restrict__ Wr,
    float* __restrict__ el, float* __restrict__ er) {
  const int lane = threadIdx.x & 63;
  const int gw = (blockIdx.x * 256 + threadIdx.x) >> 6;
  const int nw = gridDim.x * 4;
  float wl[4], wr[4];
  #pragma unroll
  for (int hh = 0; hh < 4; ++hh) {
    wl[hh] = Wl[hh * 64 + lane];
    wr[hh] = Wr[hh * 64 + lane];
  }
  for (int r = gw; r < N_NODES; r += nw) {
    float xv = x[r * 64 + lane];
    float p[4], q[4];
    #pragma unroll
    for (int hh = 0; hh < 4; ++hh) { p[hh] = xv * wl[hh]; q[hh] = xv * wr[hh]; }
    #pragma unroll
    for (int off = 32; off > 0; off >>= 1) {
      #pragma unroll
      for (int hh = 0; hh < 4; ++hh) {
        p[hh] += __shfl_xor(p[hh], off, 64);
        q[hh] += __shfl_xor(q[hh], off, 64);
      }
    }
    if (lane == 0) {
      f32x4 pv = {p[0], p[1], p[2], p[3]};
      f32x4 qv = {q[0], q[1], q[2], q[3]};
      ((f32x4*)el)[r] = pv;
      ((f32x4*)er)[r] = qv;
    }
  }
}

// ---------------- Kernel 3: XCD-sliced bucket partition ---------------------
// slice = blockIdx&7 ~ XCD id (round-robin dispatch heuristic). Each
// (bucket,slice) sub-list is filled by one XCD only -> lines written once,
// cursor atomics XCD-local with 8x less contention.
__global__ __launch_bounds__(256) void k_part(const int* __restrict__ ei,
                                              int* __restrict__ bcnt,
                                              unsigned int* __restrict__ raw) {
  int e = blockIdx.x * 256 + threadIdx.x;
  int slice = blockIdx.x & 7;
  if (e < N_EDGES) {
    int s = ei[e], d = ei[N_EDGES + e];
    int b  = s / NPB;
    int sl = s - b * NPB;
    int cell = b * NSL + slice;
    int pos = atomicAdd(&bcnt[cell * 16], 1);
    if (pos < BCAPS)
      raw[(size_t)cell * BCAPS + pos] = ((unsigned int)d << 8) | (unsigned int)sl;
  }
}

// ---------------- Kernel 4: per-bucket-half CSR + edge weights --------------
// Grid 2000: b = blk>>1, half = blk&1 handles slices 4*half..4*half+3.
__global__ __launch_bounds__(256) void k_bucket(const unsigned int* __restrict__ raw,
    const int* __restrict__ bcnt,
    const float* __restrict__ el, const float* __restrict__ er,
    int4* __restrict__ recs, int* __restrict__ rs_s, int* __restrict__ rs_e) {
  __shared__ unsigned int sraw[BCAPH];
  __shared__ int pref[NPB + 1];
  __shared__ int cur[NPB];
  const int b = blockIdx.x >> 1, H = blockIdx.x & 1, t = threadIdx.x;
  const int s0 = H * 4;
  int c0 = bcnt[(b * NSL + s0 + 0) * 16]; if (c0 > BCAPS) c0 = BCAPS;
  int c1 = bcnt[(b * NSL + s0 + 1) * 16]; if (c1 > BCAPS) c1 = BCAPS;
  int c2 = bcnt[(b * NSL + s0 + 2) * 16]; if (c2 > BCAPS) c2 = BCAPS;
  int c3 = bcnt[(b * NSL + s0 + 3) * 16]; if (c3 > BCAPS) c3 = BCAPS;
  const int o1 = c0, o2 = c0 + c1, o3 = c0 + c1 + c2, cnt = o3 + c3;
  if (t <= NPB) pref[t] = 0;
  __syncthreads();
  for (int j = t; j < c0; j += 256) { unsigned int r = raw[(size_t)(b*NSL+s0+0)*BCAPS + j]; sraw[j]      = r; atomicAdd(&pref[(int)(r & 255u) + 1], 1); }
  for (int j = t; j < c1; j += 256) { unsigned int r = raw[(size_t)(b*NSL+s0+1)*BCAPS + j]; sraw[o1 + j] = r; atomicAdd(&pref[(int)(r & 255u) + 1], 1); }
  for (int j = t; j < c2; j += 256) { unsigned int r = raw[(size_t)(b*NSL+s0+2)*BCAPS + j]; sraw[o2 + j] = r; atomicAdd(&pref[(int)(r & 255u) + 1], 1); }
  for (int j = t; j < c3; j += 256) { unsigned int r = raw[(size_t)(b*NSL+s0+3)*BCAPS + j]; sraw[o3 + j] = r; atomicAdd(&pref[(int)(r & 255u) + 1], 1); }
  __syncthreads();
  if (t == 0) {
    int run = 0;
    #pragma unroll
    for (int n = 0; n <= NPB; ++n) { run += pref[n]; pref[n] = run; }
  }
  __syncthreads();
  const int wbase = (b * 2 + H) * BCAPH;   // this half's window in recs
  if (t < NPB) {
    cur[t] = pref[t];
    rs_s[H * N_NODES + b * NPB + t] = wbase + pref[t];
    rs_e[H * N_NODES + b * NPB + t] = wbase + pref[t + 1];
  }
  __syncthreads();
  const int base = b * NPB;
  for (int j = t; j < cnt; j += 256) {
    unsigned int r = sraw[j];
    int sl = (int)(r & 255u);
    int d  = (int)(r >> 8);
    int pos = atomicAdd(&cur[sl], 1);
    f32x4 a = ((const f32x4*)el)[base + sl];   // L1-resident (800B/bucket)
    f32x4 e = ((const f32x4*)er)[d];           // L2-resident (800 KB)
    float w[4];
    #pragma unroll
    for (int hh = 0; hh < 4; ++hh) {
      float tt = a[hh] + e[hh];
      tt = (tt >= 0.f) ? tt : 0.2f * tt;
      w[hh] = __expf(tt);
    }
    union { __half2 h; int i; } u01, u23;
    u01.h = __floats2half2_rn(w[0], w[1]);
    u23.h = __floats2half2_rn(w[2], w[3]);
    int4 rc; rc.x = d; rc.y = u01.i; rc.z = u23.i; rc.w = 0;
    recs[(size_t)wbase + pos] = rc;            // scattered within 20KB window
  }
}

// ---------------- Kernel 5: fused normalize + SpMM + ELU --------------------
// One wave per node; per-node edges live in two half-ranges.
__global__ __launch_bounds__(256) void k_agg(const float* __restrict__ x,
    const int* __restrict__ rs_s, const int* __restrict__ rs_e,
    const int4* __restrict__ recs,
    const float* __restrict__ bvec, float* __restrict__ out) {
  const int node = (blockIdx.x * 256 + threadIdx.x) >> 6;
  const int lane = threadIdx.x & 63;
  if (node >= N_NODES) return;
  float n0 = 0.f, n1 = 0.f, n2 = 0.f, n3 = 0.f;
  float d0 = 0.f, d1 = 0.f, d2 = 0.f, d3 = 0.f;
  #pragma unroll
  for (int hf = 0; hf < 2; ++hf) {
    const int j0 = rs_s[hf * N_NODES + node], j1 = rs_e[hf * N_NODES + node];
    #pragma unroll 4
    for (int j = j0; j < j1; ++j) {
      int4 rec = recs[j];               // 16B wave-uniform broadcast
      union { int i; __half2 h; } u01, u23;
      u01.i = rec.y; u23.i = rec.z;
      float2 f01 = __half22float2(u01.h);
      float2 f23 = __half22float2(u23.h);
      float xv = x[rec.x * 64 + lane];  // coalesced 256B gather
      d0 += f01.x; d1 += f01.y; d2 += f23.x; d3 += f23.y;
      n0 = fmaf(f01.x, xv, n0); n1 = fmaf(f01.y, xv, n1);
      n2 = fmaf(f23.x, xv, n2); n3 = fmaf(f23.y, xv, n3);
    }
  }
  float bv = bvec[lane];
  size_t ob = (size_t)node * 256 + lane;
  float o;
  o = n0 / fmaxf(d0, 1e-12f) + bv; o = (o > 0.f) ? o : (__expf(o) - 1.f); out[ob      ] = o;
  o = n1 / fmaxf(d1, 1e-12f) + bv; o = (o > 0.f) ? o : (__expf(o) - 1.f); out[ob +  64] = o;
  o = n2 / fmaxf(d2, 1e-12f) + bv; o = (o > 0.f) ? o : (__expf(o) - 1.f); out[ob + 128] = o;
  o = n3 / fmaxf(d3, 1e-12f) + bv; o = (o > 0.f) ? o : (__expf(o) - 1.f); out[ob + 192] = o;
}

// ---------------- Launch ----------------------------------------------------
extern "C" void kernel_launch(void* const* d_in, const int* in_sizes, int n_in,
                              void* d_out, int out_size, void* d_ws, size_t ws_size,
                              hipStream_t stream) {
  const float* h  = (const float*)d_in[0];
  const float* W  = (const float*)d_in[1];
  const float* Wl = (const float*)d_in[2];
  const float* Wr = (const float*)d_in[3];
  const float* b  = (const float*)d_in[4];
  const int*   ei = (const int*)d_in[5];
  float* out = (float*)d_out;   // reference output dtype is float32

  char* ws = (char*)d_ws;
  float*        x    = (float*)       (ws + 0);          // 12,800,000
  float*        el   = (float*)       (ws + 12800000);   //    800,000
  float*        er   = (float*)       (ws + 13600000);   //    800,000
  int*          bcnt = (int*)         (ws + 14400000);   // 8000*64  =    512,000
  unsigned int* raw  = (unsigned int*)(ws + 14912000);   // 8000*320*4 = 10,240,000
  int4*         recs = (int4*)        (ws + 25152000);   // 2000*1280*16 = 40,960,000
  int*          rs_s = (int*)         (ws + 66112000);   //    400,000
  int*          rs_e = (int*)         (ws + 66512000);   //    400,000  (end ~66.9 MB)
  (void)ws_size; (void)in_sizes; (void)n_in; (void)out_size;

  hipMemsetAsync(bcnt, 0, 512000, stream);

  k_x      <<<782,   256, 0, stream>>>(h, W, x);
  k_eler   <<<782,   256, 0, stream>>>(x, Wl, Wr, el, er);
  k_part   <<<6250,  256, 0, stream>>>(ei, bcnt, raw);
  k_bucket <<<2000,  256, 0, stream>>>(raw, bcnt, el, er, recs, rs_s, rs_e);
  k_agg    <<<12500, 256, 0, stream>>>(x, rs_s, rs_e, recs, b, out);
}